// Round 7
// baseline (756.674 us; speedup 1.0000x reference)
//
#include <hip/hip_runtime.h>
#include <hip/hip_bf16.h>

#define B_SZ 8192
#define D_SZ 4096   // K
#define H_SZ 2048
#define N4H  8192   // 4*H = N (gate-interleaved n' space)
#define NT   (D_SZ / 64)   // 64 K-tiles of BK=64
#define ANX  ((size_t)256 * D_SZ)   // A advance per work (256 rows)

typedef __attribute__((ext_vector_type(8))) __bf16 bf16x8;
typedef __attribute__((ext_vector_type(4))) float f32x4;

#define GPTR(p) ((__attribute__((address_space(1))) void*)(p))
#define LPTR(p) ((__attribute__((address_space(3))) void*)(p))

// ---------------------------------------------------------------------------
// 1) prep: [blocks 0..2047]    combine = bf16(input + hidden)
//    [blocks 2048..34815]      WT[n'][k] = bf16(W_g[k][h]),
//                              n' = (h>>4)*64 + g*16 + (h&15)   (gate-interleave)
// ---------------------------------------------------------------------------
__global__ void prep_k(const float* __restrict__ x, const float* __restrict__ h,
                       __hip_bfloat16* __restrict__ comb,
                       const float* __restrict__ Wf, const float* __restrict__ Wc,
                       const float* __restrict__ Wi, const float* __restrict__ Wo,
                       __hip_bfloat16* __restrict__ WT) {
    __shared__ float t[32][33];
    if (blockIdx.x < 2048) {
        const size_t n4 = (size_t)B_SZ * D_SZ / 4;
        const size_t stride = (size_t)2048 * 256;
        for (size_t i = (size_t)blockIdx.x * 256 + threadIdx.x; i < n4; i += stride) {
            f32x4 a = __builtin_nontemporal_load((const f32x4*)x + i);
            f32x4 b = __builtin_nontemporal_load((const f32x4*)h + i);
            short4 r;
            r.x = __builtin_bit_cast(short, __float2bfloat16(a.x + b.x));
            r.y = __builtin_bit_cast(short, __float2bfloat16(a.y + b.y));
            r.z = __builtin_bit_cast(short, __float2bfloat16(a.z + b.z));
            r.w = __builtin_bit_cast(short, __float2bfloat16(a.w + b.w));
            ((short4*)comb)[i] = r;
        }
    } else {
        const int b = blockIdx.x - 2048;      // 0..32767
        const int k0 = (b & 127) * 32;        // K block
        const int n0 = (b >> 7) * 32;         // old-layout n block (g*2048 + h)
        const float* W = (n0 < H_SZ) ? Wf : (n0 < 2 * H_SZ) ? Wc
                       : (n0 < 3 * H_SZ) ? Wi : Wo;
        const int g = n0 >> 11;
        const int nc = n0 & (H_SZ - 1);
        const int tx = threadIdx.x & 31, ty = threadIdx.x >> 5;
#pragma unroll
        for (int j = 0; j < 4; ++j)
            t[ty + j * 8][tx] = __builtin_nontemporal_load(
                W + (size_t)(k0 + ty + j * 8) * H_SZ + nc + tx);
        __syncthreads();
#pragma unroll
        for (int j = 0; j < 4; ++j) {
            const int h2 = nc + ty + j * 8;                       // h index
            const int np = ((h2 >> 4) << 6) + (g << 4) + (h2 & 15);
            WT[(size_t)np * D_SZ + k0 + tx] = __float2bfloat16(t[tx][ty + j * 8]);
        }
    }
}

// ---------------------------------------------------------------------------
// 2) Persistent GEMM + fused LSTM epilogue (v4: cross-phase read pipelining).
//    256x256 tile, BK=64, 8 waves (2Mx4N). Every ds_read is issued ONE PHASE
//    before its consuming MFMA, placed AFTER the current phase's MFMA cluster
//    (WAR on the same regs is safe: in-order issue, compiler inserts hazard
//    waits). No explicit lgkmcnt — the compiler inserts minimal counted waits
//    before each consuming MFMA. Reads thus drain in the MFMA shadow:
//      ph1: MFMA q00 | read b1=qn1(t)   | stage B1(t+1)->OB | vmcnt(10) BAR
//      ph2: MFMA q01 | read a =qm1(t)   | stage A0(t+2)->CA | vmcnt(6)  BAR
//      ph3: MFMA q10 | read b0=qn0(t+1) | stage B0(t+2)->CB | vmcnt(10) BAR
//      ph4: MFMA q11 | read a =qm0(t+1) | stage A1(t+2)->CA | vmcnt(6)  BAR
//    vmcnt placed BEFORE each barrier so stage-completion is cross-wave
//    visible after it (counts audited from the stage FIFO; see per-phase
//    comments). Register set unchanged vs r6 (a 32 + b0/b1 32 VGPR) -> no
//    spill at the 256/wave cap (round-4 lesson).
// ---------------------------------------------------------------------------

#define BAR()                                    \
    do {                                         \
        asm volatile("" ::: "memory");           \
        __builtin_amdgcn_s_barrier();            \
        asm volatile("" ::: "memory");           \
    } while (0)

#define STAGE(pbase, HSTRIDE, h, kt, region)                                           \
    do {                                                                               \
        __builtin_amdgcn_global_load_lds(                                              \
            GPTR((pbase) + (size_t)((h) * (HSTRIDE)) * D_SZ + (size_t)(kt) * 64),      \
            LPTR(smem + (region) + (h) * 16384 + wave * 1024), 16, 0, 0);              \
        __builtin_amdgcn_global_load_lds(                                              \
            GPTR((pbase) + (size_t)(128 + (h) * (HSTRIDE)) * D_SZ + (size_t)(kt) * 64),\
            LPTR(smem + (region) + (h) * 16384 + 8192 + wave * 1024), 16, 0, 0);       \
    } while (0)

#define LDA(dst, base, qm)                                                             \
    do {                                                                               \
        _Pragma("unroll") for (int mi = 0; mi < 4; ++mi) {                             \
            const int row_ = (qm) * 128 + wr * 64 + mi * 16 + fr;                      \
            dst[mi][0] = *(const bf16x8*)(smem + (base) + row_ * 128 + sw0);           \
            dst[mi][1] = *(const bf16x8*)(smem + (base) + row_ * 128 + sw1);           \
        }                                                                              \
    } while (0)

#define LDB(dst, base, qn)                                                             \
    do {                                                                               \
        _Pragma("unroll") for (int nf = 0; nf < 2; ++nf) {                             \
            const int row_ = (qn) * 128 + wc * 32 + nf * 16 + fr;                      \
            dst[nf][0] = *(const bf16x8*)(smem + (base) + row_ * 128 + sw0);           \
            dst[nf][1] = *(const bf16x8*)(smem + (base) + row_ * 128 + sw1);           \
        }                                                                              \
    } while (0)

#define MFMA_Q(qm, qn, areg, breg)                                                     \
    do {                                                                               \
        _Pragma("unroll") for (int mi = 0; mi < 4; ++mi)                               \
        _Pragma("unroll") for (int nf = 0; nf < 2; ++nf)                               \
        _Pragma("unroll") for (int ks = 0; ks < 2; ++ks)                               \
            acc[(qm) * 4 + mi][(qn) * 2 + nf] =                                        \
                __builtin_amdgcn_mfma_f32_16x16x32_bf16(                               \
                    areg[mi][ks], breg[nf][ks],                                        \
                    acc[(qm) * 4 + mi][(qn) * 2 + nf], 0, 0, 0);                       \
    } while (0)

// vmcnt audit (stage FIFO; each STAGE = 2 loads, vmcnt counts loads):
//  end-ph1 needs A1(t)@ph4(t-2) landed  -> after it: B1(t),A0(t+1),B0(t+1),
//           A1(t+1),B1(t+1)             -> 5 stages  -> vmcnt(10)
//  end-ph2 needs B0(t+1)@ph3(t-1)       -> after it: A1(t+1),B1(t+1),A0(t+2)
//                                        -> 3 stages -> vmcnt(6)
//  end-ph3 needs A0(t+1)@ph2(t-1)       -> after it: B0(t+1),A1(t+1),B1(t+1),
//           A0(t+2),B0(t+2)             -> 5 stages  -> vmcnt(10)
//  end-ph4 needs B1(t)@ph1(t-1)... for next tile's ph1 read -> after it:
//           A0(t+1),B0(t+1),A1(t+1)     -> 3 stages  -> vmcnt(6)
#define TILE_P(CA, CB, OA, OB, PA2, K1, K2)                                            \
    {                                                                                  \
        /* ph1: q00 uses a=qm0(t), b0=qn0(t) (read last tile) */                       \
        __builtin_amdgcn_s_setprio(1);                                                 \
        MFMA_Q(0, 0, a, b0);                                                           \
        __builtin_amdgcn_s_setprio(0);                                                 \
        LDB(b1, CB, 1);                                                                \
        STAGE(pB, 32, 1, (K1), OB);                                                    \
        asm volatile("s_waitcnt vmcnt(10)" ::: "memory");                              \
        BAR();                                                                         \
        /* ph2: q01 uses a=qm0(t), b1; then a <- qm1(t) (WAR after MFMA) */            \
        __builtin_amdgcn_s_setprio(1);                                                 \
        MFMA_Q(0, 1, a, b1);                                                           \
        __builtin_amdgcn_s_setprio(0);                                                 \
        LDA(a, CA, 1);                                                                 \
        STAGE(PA2, 64, 0, (K2), CA);                                                   \
        asm volatile("s_waitcnt vmcnt(6)" ::: "memory");                               \
        BAR();                                                                         \
        /* ph3: q10 uses a=qm1(t), b0=qn0(t); then b0 <- qn0(t+1) from OB */           \
        __builtin_amdgcn_s_setprio(1);                                                 \
        MFMA_Q(1, 0, a, b0);                                                           \
        __builtin_amdgcn_s_setprio(0);                                                 \
        LDB(b0, OB, 0);                                                                \
        STAGE(pB, 32, 0, (K2), CB);                                                    \
        asm volatile("s_waitcnt vmcnt(10)" ::: "memory");                              \
        BAR();                                                                         \
        /* ph4: q11 uses a=qm1(t), b1; then a <- qm0(t+1) from OA */                   \
        __builtin_amdgcn_s_setprio(1);                                                 \
        MFMA_Q(1, 1, a, b1);                                                           \
        __builtin_amdgcn_s_setprio(0);                                                 \
        LDA(a, OA, 0);                                                                 \
        STAGE(PA2, 64, 1, (K2), CA);                                                   \
        asm volatile("s_waitcnt vmcnt(6)" ::: "memory");                               \
        BAR();                                                                         \
    }

__device__ __forceinline__ float fsig(float x) { return 1.f / (1.f + __expf(-x)); }
__device__ __forceinline__ float ftanh(float x) {
    x = fminf(fmaxf(x, -15.f), 15.f);
    float e = __expf(2.f * x);
    return (e - 1.f) / (e + 1.f);
}

__global__ __launch_bounds__(512, 2) void gemm8_k(
    const __hip_bfloat16* __restrict__ A,   // comb [8192][4096]
    const __hip_bfloat16* __restrict__ BT,  // WT   [8192][4096] (gate-interleaved rows)
    const float* __restrict__ cell,         // [8192][2048]
    const float* __restrict__ bfb, const float* __restrict__ bcb,
    const float* __restrict__ bib, const float* __restrict__ bob,
    float* __restrict__ out)                // [out | hid | cst], each [8192][2048]
{
    extern __shared__ char smem[];

    const int tid  = threadIdx.x;
    const int wave = tid >> 6;
    const int lane = tid & 63;
    const int wr = wave >> 2;   // 0..1
    const int wc = wave & 3;    // 0..3
    const int fr = lane & 15;
    const int sw0 = (((lane >> 4) + 0) ^ (fr & 7)) << 4;
    const int sw1 = (((lane >> 4) + 4) ^ (fr & 7)) << 4;

    // persistent mapping: fixed n-column per block, 4 m-works
    const int r0   = tid >> 3;
    const int col0 = ((tid & 7) ^ (r0 & 7)) << 3;
    const __hip_bfloat16* pB =
        BT + (size_t)((blockIdx.x >> 3) * 256 + ((r0 >> 5) << 6) + (r0 & 31)) * D_SZ + col0;
    const __hip_bfloat16* pA =
        A + (size_t)((blockIdx.x & 7) * 1024 + r0) * D_SZ + col0;   // work it=0

    f32x4 acc[8][4] = {};
    bf16x8 a[4][2], b0[2][2], b1[2][2];

    // prologue: tile0 -> buf0, tile1 A0,B0,A1 -> buf1 (invariant established)
    STAGE(pA, 64, 0, 0, 0);
    STAGE(pB, 32, 0, 0, 32768);
    STAGE(pA, 64, 1, 0, 0);
    STAGE(pB, 32, 1, 0, 32768);
    STAGE(pA, 64, 0, 1, 65536);
    STAGE(pB, 32, 0, 1, 98304);
    STAGE(pA, 64, 1, 1, 65536);
    asm volatile("s_waitcnt vmcnt(6)" ::: "memory");   // tile0 fully landed
    BAR();
    // preload tile0 operands for ph1 (consumed by q00; compiler inserts lgkm)
    LDA(a, 0, 0);
    LDB(b0, 32768, 0);

#pragma unroll 1
    for (int it = 0; it < 4; ++it) {
        // steady tiles 0..61 (no wrap inside)
#pragma unroll 1
        for (int t = 0; t < 62; t += 2) {
            TILE_P(0,     32768, 65536, 98304, pA, t + 1, t + 2);
            TILE_P(65536, 98304, 0,     32768, pA, t + 2, t + 3);
        }
        // boundary tiles 62,63: stage next work's tiles 0,1 (it=3 wraps into
        // the WT workspace region — valid memory, data unused)
        TILE_P(0,     32768, 65536, 98304, pA + ANX, 63, 0);
        TILE_P(65536, 98304, 0,     32768, pA + ANX, 0, 1);

        // ---- fused LSTM epilogue for work `it` (all state scoped here so the
        // K-loop's register live-set stays under the 256/wave cap)
        {
            const int crow = (lane >> 4) * 4;
            const int ccol = lane & 15;
            const int hh = ((blockIdx.x >> 3) * 4 + wc) * 16 + ccol;
            const float bf_ = bfb[hh], bc_ = bcb[hh], bi_ = bib[hh], bo_ = bob[hh];
            const size_t BH = (size_t)B_SZ * H_SZ;
            float* hidp = out + BH;
            float* cstp = out + 2 * BH;
            const int m0w = ((blockIdx.x & 7) * 4 + it) * 256;
#pragma unroll
            for (int ai = 0; ai < 8; ++ai) {
#pragma unroll
                for (int j = 0; j < 4; ++j) {
                    const size_t r = (size_t)(m0w + wr * 128 + ai * 16 + crow + j);
                    const size_t idx = r * H_SZ + hh;
                    const float gf = acc[ai][0][j] + bf_;
                    const float gc = acc[ai][1][j] + bc_;
                    const float gi = acc[ai][2][j] + bi_;
                    const float go = acc[ai][3][j] + bo_;
                    const float ft = fsig(gf);
                    const float ct = ftanh(gc);
                    const float it_ = fsig(fsig(gi));   // double sigmoid, faithful
                    const float ot = fsig(go);
                    const float cv = __builtin_nontemporal_load(cell + idx);
                    const float cs = cv * ft + ct * it_;
                    __builtin_nontemporal_store(ot, out + idx);
                    __builtin_nontemporal_store(cs, cstp + idx);
                    __builtin_nontemporal_store(ot * ftanh(cs), hidp + idx);
                }
            }
        }
        // reset accumulators (unconditional — last one is harmless)
#pragma unroll
        for (int ai = 0; ai < 8; ++ai)
#pragma unroll
            for (int bj = 0; bj < 4; ++bj)
                acc[ai][bj] = (f32x4){0.f, 0.f, 0.f, 0.f};
        pA += ANX;
    }

    // drain pending LDS-DMA (wrap prefetch of the last work) before endpgm
    asm volatile("s_waitcnt vmcnt(0)" ::: "memory");
}

// ---------------------------------------------------------------------------
extern "C" void kernel_launch(void* const* d_in, const int* in_sizes, int n_in,
                              void* d_out, int out_size, void* d_ws, size_t ws_size,
                              hipStream_t stream) {
    const float* input  = (const float*)d_in[0];
    const float* hidden = (const float*)d_in[1];
    const float* cell   = (const float*)d_in[2];
    const float* Wf     = (const float*)d_in[3];
    const float* bfb    = (const float*)d_in[4];
    const float* Wc     = (const float*)d_in[5];
    const float* bcb    = (const float*)d_in[6];
    const float* Wi     = (const float*)d_in[7];
    const float* bib    = (const float*)d_in[8];
    const float* Wo     = (const float*)d_in[9];
    const float* bob    = (const float*)d_in[10];
    float* out = (float*)d_out;

    char* ws = (char*)d_ws;
    __hip_bfloat16* comb = (__hip_bfloat16*)ws;                              // 64 MiB
    __hip_bfloat16* WT   = (__hip_bfloat16*)(ws + (size_t)B_SZ * D_SZ * 2);  // 64 MiB

    hipFuncSetAttribute(reinterpret_cast<const void*>(gemm8_k),
                        hipFuncAttributeMaxDynamicSharedMemorySize, 131072);

    prep_k<<<2048 + 32768, 256, 0, stream>>>(input, hidden, comb, Wf, Wc, Wi, Wo, WT);
    gemm8_k<<<256, 512, 131072, stream>>>(comb, WT, cell, bfb, bcb, bib, bob, out);
}

// Round 8
// 604.839 us; speedup vs baseline: 1.2510x; 1.2510x over previous
//
#include <hip/hip_runtime.h>
#include <hip/hip_bf16.h>

#define B_SZ 8192
#define D_SZ 4096   // K
#define H_SZ 2048
#define N4H  8192   // 4*H = N (gate-interleaved n' space)
#define NT   (D_SZ / 64)   // 64 K-tiles of BK=64
#define ANX  ((size_t)256 * D_SZ)   // A advance per work (256 rows)

typedef __attribute__((ext_vector_type(8))) __bf16 bf16x8;
typedef __attribute__((ext_vector_type(4))) float f32x4;

#define GPTR(p) ((__attribute__((address_space(1))) void*)(p))
#define LPTR(p) ((__attribute__((address_space(3))) void*)(p))

// ---------------------------------------------------------------------------
// 1) prep: [blocks 0..2047]    combine = bf16(input + hidden)
//    [blocks 2048..34815]      WT[n'][k] = bf16(W_g[k][h]),
//                              n' = (h>>4)*64 + g*16 + (h&15)   (gate-interleave)
// ---------------------------------------------------------------------------
__global__ void prep_k(const float* __restrict__ x, const float* __restrict__ h,
                       __hip_bfloat16* __restrict__ comb,
                       const float* __restrict__ Wf, const float* __restrict__ Wc,
                       const float* __restrict__ Wi, const float* __restrict__ Wo,
                       __hip_bfloat16* __restrict__ WT) {
    __shared__ float t[32][33];
    if (blockIdx.x < 2048) {
        const size_t n4 = (size_t)B_SZ * D_SZ / 4;
        const size_t stride = (size_t)2048 * 256;
        for (size_t i = (size_t)blockIdx.x * 256 + threadIdx.x; i < n4; i += stride) {
            f32x4 a = __builtin_nontemporal_load((const f32x4*)x + i);
            f32x4 b = __builtin_nontemporal_load((const f32x4*)h + i);
            short4 r;
            r.x = __builtin_bit_cast(short, __float2bfloat16(a.x + b.x));
            r.y = __builtin_bit_cast(short, __float2bfloat16(a.y + b.y));
            r.z = __builtin_bit_cast(short, __float2bfloat16(a.z + b.z));
            r.w = __builtin_bit_cast(short, __float2bfloat16(a.w + b.w));
            ((short4*)comb)[i] = r;
        }
    } else {
        const int b = blockIdx.x - 2048;      // 0..32767
        const int k0 = (b & 127) * 32;        // K block
        const int n0 = (b >> 7) * 32;         // old-layout n block (g*2048 + h)
        const float* W = (n0 < H_SZ) ? Wf : (n0 < 2 * H_SZ) ? Wc
                       : (n0 < 3 * H_SZ) ? Wi : Wo;
        const int g = n0 >> 11;
        const int nc = n0 & (H_SZ - 1);
        const int tx = threadIdx.x & 31, ty = threadIdx.x >> 5;
#pragma unroll
        for (int j = 0; j < 4; ++j)
            t[ty + j * 8][tx] = __builtin_nontemporal_load(
                W + (size_t)(k0 + ty + j * 8) * H_SZ + nc + tx);
        __syncthreads();
#pragma unroll
        for (int j = 0; j < 4; ++j) {
            const int h2 = nc + ty + j * 8;                       // h index
            const int np = ((h2 >> 4) << 6) + (g << 4) + (h2 & 15);
            WT[(size_t)np * D_SZ + k0 + tx] = __float2bfloat16(t[tx][ty + j * 8]);
        }
    }
}

// ---------------------------------------------------------------------------
// 2) Persistent GEMM + fused LSTM epilogue (v5 = round-6 structure WITHOUT the
//    explicit lgkmcnt(0) between ds_reads and MFMA).
//    Rationale: the explicit full drain forced all 12 reads complete before
//    ANY MFMA issued -> LDS pipe and MFMA pipe strictly serialized. hipcc
//    left alone emits COUNTED lgkm waits per consuming MFMA (m97 asm
//    evidence), so the first MFMA starts when its own fragments land and the
//    remaining reads drain under the MFMA cluster. Reads stay BEFORE the
//    MFMAs in program order (no WAR hazard — same ordering r6 proved safe).
//    Barriers, vmcnt(6) accounting, staging regions identical to round 6.
// ---------------------------------------------------------------------------

#define BAR()                                    \
    do {                                         \
        asm volatile("" ::: "memory");           \
        __builtin_amdgcn_s_barrier();            \
        asm volatile("" ::: "memory");           \
    } while (0)

#define STAGE(pbase, HSTRIDE, h, kt, region)                                           \
    do {                                                                               \
        __builtin_amdgcn_global_load_lds(                                              \
            GPTR((pbase) + (size_t)((h) * (HSTRIDE)) * D_SZ + (size_t)(kt) * 64),      \
            LPTR(smem + (region) + (h) * 16384 + wave * 1024), 16, 0, 0);              \
        __builtin_amdgcn_global_load_lds(                                              \
            GPTR((pbase) + (size_t)(128 + (h) * (HSTRIDE)) * D_SZ + (size_t)(kt) * 64),\
            LPTR(smem + (region) + (h) * 16384 + 8192 + wave * 1024), 16, 0, 0);       \
    } while (0)

#define LDA(dst, base, qm)                                                             \
    do {                                                                               \
        _Pragma("unroll") for (int mi = 0; mi < 4; ++mi) {                             \
            const int row_ = (qm) * 128 + wr * 64 + mi * 16 + fr;                      \
            dst[mi][0] = *(const bf16x8*)(smem + (base) + row_ * 128 + sw0);           \
            dst[mi][1] = *(const bf16x8*)(smem + (base) + row_ * 128 + sw1);           \
        }                                                                              \
    } while (0)

#define LDB(dst, base, qn)                                                             \
    do {                                                                               \
        _Pragma("unroll") for (int nf = 0; nf < 2; ++nf) {                             \
            const int row_ = (qn) * 128 + wc * 32 + nf * 16 + fr;                      \
            dst[nf][0] = *(const bf16x8*)(smem + (base) + row_ * 128 + sw0);           \
            dst[nf][1] = *(const bf16x8*)(smem + (base) + row_ * 128 + sw1);           \
        }                                                                              \
    } while (0)

#define MFMA_Q(qm, qn, areg, breg)                                                     \
    do {                                                                               \
        _Pragma("unroll") for (int mi = 0; mi < 4; ++mi)                               \
        _Pragma("unroll") for (int nf = 0; nf < 2; ++nf)                               \
        _Pragma("unroll") for (int ks = 0; ks < 2; ++ks)                               \
            acc[(qm) * 4 + mi][(qn) * 2 + nf] =                                        \
                __builtin_amdgcn_mfma_f32_16x16x32_bf16(                               \
                    areg[mi][ks], breg[nf][ks],                                        \
                    acc[(qm) * 4 + mi][(qn) * 2 + nf], 0, 0, 0);                       \
    } while (0)

// One K-tile, 4 phases, ONE barrier per phase (after MFMA). STAGE targets as
// round 6 (each region's last reader drained >=1 barrier before the stage).
// No explicit lgkm between reads and MFMA: compiler inserts counted waits so
// trailing reads drain under the MFMA cluster. vmcnt(6) before the final BAR
// => tile t+1 fully landed, newest 3 STAGEs in flight.
#define TILE_FULL(CA, CB, OB, PA2, K1, K2)                                             \
    {                                                                                  \
        LDA(a, CA, 0);                                                                 \
        LDB(b0, CB, 0);                                                                \
        STAGE(pB, 32, 1, (K1), OB);                                                    \
        __builtin_amdgcn_s_setprio(1);                                                 \
        MFMA_Q(0, 0, a, b0);                                                           \
        __builtin_amdgcn_s_setprio(0);                                                 \
        BAR();                                                                         \
        LDB(b1, CB, 1);                                                                \
        STAGE(PA2, 64, 0, (K2), CA);                                                   \
        __builtin_amdgcn_s_setprio(1);                                                 \
        MFMA_Q(0, 1, a, b1);                                                           \
        __builtin_amdgcn_s_setprio(0);                                                 \
        BAR();                                                                         \
        LDA(a, CA, 1);                                                                 \
        STAGE(pB, 32, 0, (K2), CB);                                                    \
        __builtin_amdgcn_s_setprio(1);                                                 \
        MFMA_Q(1, 0, a, b0);                                                           \
        __builtin_amdgcn_s_setprio(0);                                                 \
        BAR();                                                                         \
        STAGE(PA2, 64, 1, (K2), CA);                                                   \
        __builtin_amdgcn_s_setprio(1);                                                 \
        MFMA_Q(1, 1, a, b1);                                                           \
        __builtin_amdgcn_s_setprio(0);                                                 \
        asm volatile("s_waitcnt vmcnt(6)" ::: "memory");                               \
        BAR();                                                                         \
    }

__device__ __forceinline__ float fsig(float x) { return 1.f / (1.f + __expf(-x)); }
__device__ __forceinline__ float ftanh(float x) {
    x = fminf(fmaxf(x, -15.f), 15.f);
    float e = __expf(2.f * x);
    return (e - 1.f) / (e + 1.f);
}

__global__ __launch_bounds__(512, 2) void gemm8_k(
    const __hip_bfloat16* __restrict__ A,   // comb [8192][4096]
    const __hip_bfloat16* __restrict__ BT,  // WT   [8192][4096] (gate-interleaved rows)
    const float* __restrict__ cell,         // [8192][2048]
    const float* __restrict__ bfb, const float* __restrict__ bcb,
    const float* __restrict__ bib, const float* __restrict__ bob,
    float* __restrict__ out)                // [out | hid | cst], each [8192][2048]
{
    extern __shared__ char smem[];

    const int tid  = threadIdx.x;
    const int wave = tid >> 6;
    const int lane = tid & 63;
    const int wr = wave >> 2;   // 0..1
    const int wc = wave & 3;    // 0..3
    const int fr = lane & 15;
    const int sw0 = (((lane >> 4) + 0) ^ (fr & 7)) << 4;
    const int sw1 = (((lane >> 4) + 4) ^ (fr & 7)) << 4;

    // persistent mapping: fixed n-column per block, 4 m-works
    const int r0   = tid >> 3;
    const int col0 = ((tid & 7) ^ (r0 & 7)) << 3;
    const __hip_bfloat16* pB =
        BT + (size_t)((blockIdx.x >> 3) * 256 + ((r0 >> 5) << 6) + (r0 & 31)) * D_SZ + col0;
    const __hip_bfloat16* pA =
        A + (size_t)((blockIdx.x & 7) * 1024 + r0) * D_SZ + col0;   // work it=0

    f32x4 acc[8][4] = {};
    bf16x8 a[4][2], b0[2][2], b1[2][2];

    // prologue: tile0 -> buf0, tile1 A0,B0,A1 -> buf1 (invariant established)
    STAGE(pA, 64, 0, 0, 0);
    STAGE(pB, 32, 0, 0, 32768);
    STAGE(pA, 64, 1, 0, 0);
    STAGE(pB, 32, 1, 0, 32768);
    STAGE(pA, 64, 0, 1, 65536);
    STAGE(pB, 32, 0, 1, 98304);
    STAGE(pA, 64, 1, 1, 65536);
    asm volatile("s_waitcnt vmcnt(6)" ::: "memory");
    BAR();

#pragma unroll 1
    for (int it = 0; it < 4; ++it) {
        // steady tiles 0..61 (no wrap inside)
#pragma unroll 1
        for (int t = 0; t < 62; t += 2) {
            TILE_FULL(0,     32768, 98304, pA, t + 1, t + 2);
            TILE_FULL(65536, 98304, 32768, pA, t + 2, t + 3);
        }
        // boundary tiles 62,63: stage next work's tiles 0,1 (it=3 wraps into
        // the WT workspace region — valid memory, data unused)
        TILE_FULL(0,     32768, 98304, pA + ANX, 63, 0);
        TILE_FULL(65536, 98304, 32768, pA + ANX, 0, 1);

        // ---- fused LSTM epilogue for work `it` (all state scoped here so the
        // K-loop's register live-set stays under the 256/wave cap)
        {
            const int crow = (lane >> 4) * 4;
            const int ccol = lane & 15;
            const int hh = ((blockIdx.x >> 3) * 4 + wc) * 16 + ccol;
            const float bf_ = bfb[hh], bc_ = bcb[hh], bi_ = bib[hh], bo_ = bob[hh];
            const size_t BH = (size_t)B_SZ * H_SZ;
            float* hidp = out + BH;
            float* cstp = out + 2 * BH;
            const int m0w = ((blockIdx.x & 7) * 4 + it) * 256;
#pragma unroll
            for (int ai = 0; ai < 8; ++ai) {
#pragma unroll
                for (int j = 0; j < 4; ++j) {
                    const size_t r = (size_t)(m0w + wr * 128 + ai * 16 + crow + j);
                    const size_t idx = r * H_SZ + hh;
                    const float gf = acc[ai][0][j] + bf_;
                    const float gc = acc[ai][1][j] + bc_;
                    const float gi = acc[ai][2][j] + bi_;
                    const float go = acc[ai][3][j] + bo_;
                    const float ft = fsig(gf);
                    const float ct = ftanh(gc);
                    const float it_ = fsig(fsig(gi));   // double sigmoid, faithful
                    const float ot = fsig(go);
                    const float cv = __builtin_nontemporal_load(cell + idx);
                    const float cs = cv * ft + ct * it_;
                    __builtin_nontemporal_store(ot, out + idx);
                    __builtin_nontemporal_store(cs, cstp + idx);
                    __builtin_nontemporal_store(ot * ftanh(cs), hidp + idx);
                }
            }
        }
        // reset accumulators (unconditional — last one is harmless)
#pragma unroll
        for (int ai = 0; ai < 8; ++ai)
#pragma unroll
            for (int bj = 0; bj < 4; ++bj)
                acc[ai][bj] = (f32x4){0.f, 0.f, 0.f, 0.f};
        pA += ANX;
    }

    // drain pending LDS-DMA (wrap prefetch of the last work) before endpgm
    asm volatile("s_waitcnt vmcnt(0)" ::: "memory");
}

// ---------------------------------------------------------------------------
extern "C" void kernel_launch(void* const* d_in, const int* in_sizes, int n_in,
                              void* d_out, int out_size, void* d_ws, size_t ws_size,
                              hipStream_t stream) {
    const float* input  = (const float*)d_in[0];
    const float* hidden = (const float*)d_in[1];
    const float* cell   = (const float*)d_in[2];
    const float* Wf     = (const float*)d_in[3];
    const float* bfb    = (const float*)d_in[4];
    const float* Wc     = (const float*)d_in[5];
    const float* bcb    = (const float*)d_in[6];
    const float* Wi     = (const float*)d_in[7];
    const float* bib    = (const float*)d_in[8];
    const float* Wo     = (const float*)d_in[9];
    const float* bob    = (const float*)d_in[10];
    float* out = (float*)d_out;

    char* ws = (char*)d_ws;
    __hip_bfloat16* comb = (__hip_bfloat16*)ws;                              // 64 MiB
    __hip_bfloat16* WT   = (__hip_bfloat16*)(ws + (size_t)B_SZ * D_SZ * 2);  // 64 MiB

    hipFuncSetAttribute(reinterpret_cast<const void*>(gemm8_k),
                        hipFuncAttributeMaxDynamicSharedMemorySize, 131072);

    prep_k<<<2048 + 32768, 256, 0, stream>>>(input, hidden, comb, Wf, Wc, Wi, Wo, WT);
    gemm8_k<<<256, 512, 131072, stream>>>(comb, WT, cell, bfb, bcb, bib, bob, out);
}

// Round 9
// 597.687 us; speedup vs baseline: 1.2660x; 1.0120x over previous
//
#include <hip/hip_runtime.h>
#include <hip/hip_bf16.h>

#define B_SZ 8192
#define D_SZ 4096   // K
#define H_SZ 2048
#define N4H  8192   // 4*H = N (gate-interleaved n' space)
#define NT   (D_SZ / 64)   // 64 K-tiles of BK=64

typedef __attribute__((ext_vector_type(8))) __bf16 bf16x8;
typedef __attribute__((ext_vector_type(4))) float f32x4;

#define GPTR(p) ((__attribute__((address_space(1))) void*)(p))
#define LPTR(p) ((__attribute__((address_space(3))) void*)(p))

// ---------------------------------------------------------------------------
// 1) prep: [blocks 0..2047]    combine = bf16(input + hidden)
//    [blocks 2048..34815]      WT[n'][k] = bf16(W_g[k][h]),
//                              n' = (h>>4)*64 + g*16 + (h&15)   (gate-interleave)
// ---------------------------------------------------------------------------
__global__ void prep_k(const float* __restrict__ x, const float* __restrict__ h,
                       __hip_bfloat16* __restrict__ comb,
                       const float* __restrict__ Wf, const float* __restrict__ Wc,
                       const float* __restrict__ Wi, const float* __restrict__ Wo,
                       __hip_bfloat16* __restrict__ WT) {
    __shared__ float t[32][33];
    if (blockIdx.x < 2048) {
        const size_t n4 = (size_t)B_SZ * D_SZ / 4;
        const size_t stride = (size_t)2048 * 256;
        for (size_t i = (size_t)blockIdx.x * 256 + threadIdx.x; i < n4; i += stride) {
            f32x4 a = __builtin_nontemporal_load((const f32x4*)x + i);
            f32x4 b = __builtin_nontemporal_load((const f32x4*)h + i);
            short4 r;
            r.x = __builtin_bit_cast(short, __float2bfloat16(a.x + b.x));
            r.y = __builtin_bit_cast(short, __float2bfloat16(a.y + b.y));
            r.z = __builtin_bit_cast(short, __float2bfloat16(a.z + b.z));
            r.w = __builtin_bit_cast(short, __float2bfloat16(a.w + b.w));
            ((short4*)comb)[i] = r;
        }
    } else {
        const int b = blockIdx.x - 2048;      // 0..32767
        const int k0 = (b & 127) * 32;        // K block
        const int n0 = (b >> 7) * 32;         // old-layout n block (g*2048 + h)
        const float* W = (n0 < H_SZ) ? Wf : (n0 < 2 * H_SZ) ? Wc
                       : (n0 < 3 * H_SZ) ? Wi : Wo;
        const int g = n0 >> 11;
        const int nc = n0 & (H_SZ - 1);
        const int tx = threadIdx.x & 31, ty = threadIdx.x >> 5;
#pragma unroll
        for (int j = 0; j < 4; ++j)
            t[ty + j * 8][tx] = __builtin_nontemporal_load(
                W + (size_t)(k0 + ty + j * 8) * H_SZ + nc + tx);
        __syncthreads();
#pragma unroll
        for (int j = 0; j < 4; ++j) {
            const int h2 = nc + ty + j * 8;                       // h index
            const int np = ((h2 >> 4) << 6) + (g << 4) + (h2 & 15);
            WT[(size_t)np * D_SZ + k0 + tx] = __float2bfloat16(t[tx][ty + j * 8]);
        }
    }
}

// ---------------------------------------------------------------------------
// 2) GEMM + fused LSTM epilogue (v6: 2 independent blocks per CU).
//    Tile 256(M)x128(N), BK=64, 4 waves (2Mx2N), wave-tile 128x64 (unchanged
//    per-wave read:MFMA ratio and register set). LDS 64KB per block:
//      A0 [128 rows][128B] @ 0      (single-buffered, recycled per phase)
//      A1 [128 rows][128B] @ 16384
//      Bb [2 bufs][128 rows][128B] @ 32768 / 49152  (double-buffered)
//    A lds row (region h): wr*64 + mi*16 + fr  <-> tile row wr*128 + h*64 + ...
//    B lds row (buf):      qn*64 + wc*32 + nf*16 + fr <-> n wc*64 + qn*32 + ...
//    All stages load tile t+1; uniform vmcnt(6) at EVERY phase end:
//      steady in-flight after ph4 = {B1(t+1):2, A1(t+1):4}; ph1 +B0 -> drains
//      B1(t) (read ph2), ph2 +A0 -> drains A1(t) (read ph3), ph3 +B1 -> drains
//      B0(t+1), ph4 +A1 -> drains A0(t+1) (read ph1(t+1)).  All 3-phase
//      windows (~1800cy) > HBM latency. WAR: each staged region's only ds_read
//      was 1 phase earlier, completed before that phase's MFMAs issued
//      (compiler counted lgkm), barrier between (r6/r8-proven argument).
//    2 blocks/CU (LDS 2x64KB=128<=160; __launch_bounds__(256,2) caps VGPR)
//    slip freely against each other -> LDS-read bursts of one block overlap
//    MFMA bursts of the other (the m97 mechanism, at 1.125 ratio).
// ---------------------------------------------------------------------------

#define LDS_A0 0
#define LDS_A1 16384
#define LDS_BB0 32768
#define LDS_BB1 49152

#define BAR()                                    \
    do {                                         \
        asm volatile("" ::: "memory");           \
        __builtin_amdgcn_s_barrier();            \
        asm volatile("" ::: "memory");           \
    } while (0)

// A quadrant h of K-tile kt -> region LDS_A0/A1 (4 calls x 32 rows x 128B)
#define STAGE_A(h, kt)                                                                 \
    do {                                                                               \
        _Pragma("unroll") for (int c_ = 0; c_ < 4; ++c_) {                             \
            __builtin_amdgcn_global_load_lds(                                          \
                GPTR(pA + (size_t)((c_ >> 1) * 128 + (h) * 64 + (c_ & 1) * 32) * D_SZ  \
                         + (size_t)(kt) * 64),                                         \
                LPTR(smem + (h) * 16384 + c_ * 4096 + wave * 1024), 16, 0, 0);         \
        }                                                                              \
    } while (0)

// B quadrant qn of K-tile kt -> buffer bb (2 calls x 32 rows x 128B)
#define STAGE_B(qn, kt, bb)                                                            \
    do {                                                                               \
        _Pragma("unroll") for (int c_ = 0; c_ < 2; ++c_) {                             \
            __builtin_amdgcn_global_load_lds(                                          \
                GPTR(pB + (size_t)((qn) * 32 + c_ * 64) * D_SZ + (size_t)(kt) * 64),   \
                LPTR(smem + (bb) + (qn) * 8192 + c_ * 4096 + wave * 1024), 16, 0, 0);  \
        }                                                                              \
    } while (0)

#define LDA(dst, RB)                                                                   \
    do {                                                                               \
        _Pragma("unroll") for (int mi = 0; mi < 4; ++mi) {                             \
            const int row_ = wr * 64 + mi * 16 + fr;                                   \
            dst[mi][0] = *(const bf16x8*)(smem + (RB) + row_ * 128 + sw0);             \
            dst[mi][1] = *(const bf16x8*)(smem + (RB) + row_ * 128 + sw1);             \
        }                                                                              \
    } while (0)

#define LDB(dst, BB, qn)                                                               \
    do {                                                                               \
        _Pragma("unroll") for (int nf = 0; nf < 2; ++nf) {                             \
            const int row_ = (qn) * 64 + wc * 32 + nf * 16 + fr;                       \
            dst[nf][0] = *(const bf16x8*)(smem + (BB) + row_ * 128 + sw0);             \
            dst[nf][1] = *(const bf16x8*)(smem + (BB) + row_ * 128 + sw1);             \
        }                                                                              \
    } while (0)

#define MFMA_Q(qm, qn, areg, breg)                                                     \
    do {                                                                               \
        _Pragma("unroll") for (int mi = 0; mi < 4; ++mi)                               \
        _Pragma("unroll") for (int nf = 0; nf < 2; ++nf)                               \
        _Pragma("unroll") for (int ks = 0; ks < 2; ++ks)                               \
            acc[(qm) * 4 + mi][(qn) * 2 + nf] =                                        \
                __builtin_amdgcn_mfma_f32_16x16x32_bf16(                               \
                    areg[mi][ks], breg[nf][ks],                                        \
                    acc[(qm) * 4 + mi][(qn) * 2 + nf], 0, 0, 0);                       \
    } while (0)

// One K-tile: 4 phases, 1 barrier each, vmcnt(6) every phase end.
#define TILE(KT, CURB, OTHB)                                                           \
    {                                                                                  \
        const int kt_ = (KT) & 63;                                                     \
        /* ph1: q(0,0); reads A0(t),B0(t); stages B0(t+1)->other buf */                \
        LDA(a, LDS_A0);                                                                \
        LDB(b0, CURB, 0);                                                              \
        STAGE_B(0, kt_, OTHB);                                                         \
        __builtin_amdgcn_s_setprio(1);                                                 \
        MFMA_Q(0, 0, a, b0);                                                           \
        __builtin_amdgcn_s_setprio(0);                                                 \
        asm volatile("s_waitcnt vmcnt(6)" ::: "memory");                               \
        BAR();                                                                         \
        /* ph2: q(0,1); reads B1(t); stages A0(t+1) (A0 read done @ph1) */             \
        LDB(b1, CURB, 1);                                                              \
        STAGE_A(0, kt_);                                                               \
        __builtin_amdgcn_s_setprio(1);                                                 \
        MFMA_Q(0, 1, a, b1);                                                           \
        __builtin_amdgcn_s_setprio(0);                                                 \
        asm volatile("s_waitcnt vmcnt(6)" ::: "memory");                               \
        BAR();                                                                         \
        /* ph3: q(1,0); reads A1(t); stages B1(t+1)->other buf */                      \
        LDA(a, LDS_A1);                                                                \
        STAGE_B(1, kt_, OTHB);                                                         \
        __builtin_amdgcn_s_setprio(1);                                                 \
        MFMA_Q(1, 0, a, b0);                                                           \
        __builtin_amdgcn_s_setprio(0);                                                 \
        asm volatile("s_waitcnt vmcnt(6)" ::: "memory");                               \
        BAR();                                                                         \
        /* ph4: q(1,1); stages A1(t+1) (A1 read done @ph3) */                          \
        STAGE_A(1, kt_);                                                               \
        __builtin_amdgcn_s_setprio(1);                                                 \
        MFMA_Q(1, 1, a, b1);                                                           \
        __builtin_amdgcn_s_setprio(0);                                                 \
        asm volatile("s_waitcnt vmcnt(6)" ::: "memory");                               \
        BAR();                                                                         \
    }

__device__ __forceinline__ float fsig(float x) { return 1.f / (1.f + __expf(-x)); }
__device__ __forceinline__ float ftanh(float x) {
    x = fminf(fmaxf(x, -15.f), 15.f);
    float e = __expf(2.f * x);
    return (e - 1.f) / (e + 1.f);
}

__global__ __launch_bounds__(256, 2) void gemm4_k(
    const __hip_bfloat16* __restrict__ A,   // comb [8192][4096]
    const __hip_bfloat16* __restrict__ BT,  // WT   [8192][4096] (gate-interleaved rows)
    const float* __restrict__ cell,         // [8192][2048]
    const float* __restrict__ bfb, const float* __restrict__ bcb,
    const float* __restrict__ bib, const float* __restrict__ bob,
    float* __restrict__ out)                // [out | hid | cst], each [8192][2048]
{
    extern __shared__ char smem[];

    const int tid  = threadIdx.x;
    const int wave = tid >> 6;
    const int lane = tid & 63;
    const int wr = wave >> 1;   // 0..1  (M halves of 128)
    const int wc = wave & 1;    // 0..1  (N halves of 64)
    const int fr = lane & 15;
    const int sw0 = (((lane >> 4) + 0) ^ (fr & 7)) << 4;
    const int sw1 = (((lane >> 4) + 4) ^ (fr & 7)) << 4;

    // XCD-aware swizzle (bijective: 2048 % 8 == 0). n fastest -> the ~64
    // co-resident blocks of an XCD share one 2MB A-panel (L2-resident).
    const int wg = (blockIdx.x & 7) * 256 + (blockIdx.x >> 3);
    const int ntile = wg & 63;
    const int m0 = (wg >> 6) * 256;
    const int n0 = ntile * 128;

    // per-thread staging sources (pre-swizzled global column; 32-row calls)
    const int r0   = tid >> 3;                           // 0..31
    const int col0 = ((tid & 7) ^ (r0 & 7)) << 3;
    const __hip_bfloat16* pA = A  + (size_t)(m0 + r0) * D_SZ + col0;
    const __hip_bfloat16* pB = BT + (size_t)(n0 + r0) * D_SZ + col0;

    f32x4 acc[8][4] = {};
    bf16x8 a[4][2], b0[2][2], b1[2][2];

    // prologue: stage tile0 in steady-state order (B0,A0,B1,A1); vmcnt(6)
    // drains B0+A0 (needed ph1), leaves B1+A1 in flight = steady invariant.
    STAGE_B(0, 0, LDS_BB0);
    STAGE_A(0, 0);
    STAGE_B(1, 0, LDS_BB0);
    STAGE_A(1, 0);
    asm volatile("s_waitcnt vmcnt(6)" ::: "memory");
    BAR();

#pragma unroll 1
    for (int t = 0; t < NT; t += 2) {
        TILE(t + 1, LDS_BB0, LDS_BB1);   // even tile t: B(t) in buf0
        TILE(t + 2, LDS_BB1, LDS_BB0);   // odd tile t+1: B in buf1 (t=63: kt wraps to 0, dummy)
    }

    // ---- fused LSTM epilogue (state scoped here; K-loop live set small)
    {
        const int crow = (lane >> 4) * 4;
        const int ccol = lane & 15;
        const int hh = (ntile * 2 + wc) * 16 + ccol;
        const float bf_ = bfb[hh], bc_ = bcb[hh], bi_ = bib[hh], bo_ = bob[hh];
        const size_t BH = (size_t)B_SZ * H_SZ;
        float* hidp = out + BH;
        float* cstp = out + 2 * BH;
#pragma unroll
        for (int ai = 0; ai < 8; ++ai) {
#pragma unroll
            for (int j = 0; j < 4; ++j) {
                const size_t r = (size_t)(m0 + wr * 128 + ai * 16 + crow + j);
                const size_t idx = r * H_SZ + hh;
                const float gf = acc[ai][0][j] + bf_;
                const float gc = acc[ai][1][j] + bc_;
                const float gi = acc[ai][2][j] + bi_;
                const float go = acc[ai][3][j] + bo_;
                const float ft = fsig(gf);
                const float ct = ftanh(gc);
                const float it_ = fsig(fsig(gi));   // double sigmoid, faithful
                const float ot = fsig(go);
                const float cv = __builtin_nontemporal_load(cell + idx);
                const float cs = cv * ft + ct * it_;
                __builtin_nontemporal_store(ot, out + idx);
                __builtin_nontemporal_store(cs, cstp + idx);
                __builtin_nontemporal_store(ot * ftanh(cs), hidp + idx);
            }
        }
    }

    // drain pending LDS-DMA (tile-63's dummy stages) before endpgm:
    // the next block on this CU reuses the LDS.
    asm volatile("s_waitcnt vmcnt(0)" ::: "memory");
}

// ---------------------------------------------------------------------------
extern "C" void kernel_launch(void* const* d_in, const int* in_sizes, int n_in,
                              void* d_out, int out_size, void* d_ws, size_t ws_size,
                              hipStream_t stream) {
    const float* input  = (const float*)d_in[0];
    const float* hidden = (const float*)d_in[1];
    const float* cell   = (const float*)d_in[2];
    const float* Wf     = (const float*)d_in[3];
    const float* bfb    = (const float*)d_in[4];
    const float* Wc     = (const float*)d_in[5];
    const float* bcb    = (const float*)d_in[6];
    const float* Wi     = (const float*)d_in[7];
    const float* bib    = (const float*)d_in[8];
    const float* Wo     = (const float*)d_in[9];
    const float* bob    = (const float*)d_in[10];
    float* out = (float*)d_out;

    char* ws = (char*)d_ws;
    __hip_bfloat16* comb = (__hip_bfloat16*)ws;                              // 64 MiB
    __hip_bfloat16* WT   = (__hip_bfloat16*)(ws + (size_t)B_SZ * D_SZ * 2);  // 64 MiB

    hipFuncSetAttribute(reinterpret_cast<const void*>(gemm4_k),
                        hipFuncAttributeMaxDynamicSharedMemorySize, 65536);

    prep_k<<<2048 + 32768, 256, 0, stream>>>(input, hidden, comb, Wf, Wc, Wi, Wo, WT);
    gemm4_k<<<2048, 256, 65536, stream>>>(comb, WT, cell, bfb, bcb, bib, bob, out);
}